// Round 10
// baseline (364.730 us; speedup 1.0000x reference)
//
#include <hip/hip_runtime.h>
#include <math.h>

#define B_SZ    2
#define L_SEQ   1024
#define DMODEL  1024
#define DINNER  2048
#define DSTATE  16
#define EPSV    1e-6f

// scan decomposition: 16 channels/block, 64 chunks of 16 steps, 1024 thr/block
#define CCH 64
#define CS  (L_SEQ / CCH)      // 16
#define DT  16
#define SSTR2 (CCH * DT + 2)   // +2 ushort pad (1 dword) to stagger s-groups

typedef short  bf16x8  __attribute__((ext_vector_type(8)));
typedef float  floatx4 __attribute__((ext_vector_type(4)));
typedef unsigned short ushort8v __attribute__((ext_vector_type(8)));

extern "C" __device__ float __ocml_native_exp2_f32(float);
extern "C" __device__ float __ocml_native_log2_f32(float);

__device__ __forceinline__ float nexp2(float x) { return __ocml_native_exp2_f32(x); }

__device__ __forceinline__ float softplus_f(float v) {
    if (v > 20.f) return v;
    return 0.69314718f * __ocml_native_log2_f32(1.f + nexp2(v * 1.44269504f));
}
__device__ __forceinline__ float silu_f(float z) {
    return z / (1.f + nexp2(z * -1.44269504f));
}

__device__ __forceinline__ unsigned short f2bf(float f) {
    unsigned int u = __float_as_uint(f);
    unsigned int r = (u + 0x7FFFu + ((u >> 16) & 1u)) >> 16;
    return (unsigned short)r;
}
__device__ __forceinline__ float bf2f(unsigned short u) {
    return __uint_as_float(((unsigned int)u) << 16);
}

// ---------------------------------------------------------------------------
// Fused prep: 3 weight transposes (+cast) and the x cast, one launch.
// blocks [0,4096) W_in; [4096,8192) W_dt; [8192,10240) W_out;
// [10240,12288) cast x -> x_bf
// ---------------------------------------------------------------------------
__global__ __launch_bounds__(256) void prep_kernel(
    const float* __restrict__ x, unsigned short* __restrict__ x_bf,
    const float* __restrict__ W_in, unsigned short* __restrict__ W_in_t,
    const float* __restrict__ W_dt, unsigned short* __restrict__ W_dt_t,
    const float* __restrict__ W_out, unsigned short* __restrict__ W_out_t)
{
    const int bid = blockIdx.x;
    if (bid >= 10240) {
        const int i = (bid - 10240) * 256 + threadIdx.x;
        float4 v = ((const float4*)x)[i];
        ushort4 o = { f2bf(v.x), f2bf(v.y), f2bf(v.z), f2bf(v.w) };
        ((ushort4*)x_bf)[i] = o;
        return;
    }
    __shared__ float tile[32][33];
    const float* W; unsigned short* Wt; int K, N, t;
    if (bid < 4096)      { W = W_in;  Wt = W_in_t;  K = 1024; N = 4096; t = bid; }
    else if (bid < 8192) { W = W_dt;  Wt = W_dt_t;  K = 2048; N = 2048; t = bid - 4096; }
    else                 { W = W_out; Wt = W_out_t; K = 2048; N = 1024; t = bid - 8192; }
    const int nx = N >> 5;
    const int n0 = (t % nx) * 32;
    const int k0 = (t / nx) * 32;
    const int c = threadIdx.x & 31;
    const int r = threadIdx.x >> 5;
#pragma unroll
    for (int i = 0; i < 4; ++i)
        tile[r + 8 * i][c] = W[(size_t)(k0 + r + 8 * i) * N + n0 + c];
    __syncthreads();
#pragma unroll
    for (int i = 0; i < 4; ++i)
        Wt[(size_t)(n0 + r + 8 * i) * K + k0 + c] = f2bf(tile[c][r + 8 * i]);
}

// ---------------------------------------------------------------------------
// bf16 MFMA GEMM — register-prefetch, single-buffered LDS, BK=64.
// 2x2 waves, wave tile (TM/2)x(TN/2). XOR-swizzled, vmcnt drains post-compute.
// MODE 0: +bias; 1: softplus(+bias); 2: +bias + resid;
// 4: softplus(+bias) -> bf16 TRANSPOSED output Ct[col][row]
// MINW: launch_bounds min-waves/EU (2 for 128x128, 3 for smaller tiles).
// ---------------------------------------------------------------------------
template <int TM, int TN, int MODE, int MINW>
__global__ __launch_bounds__(256, MINW) void gemm_bf16(
    const unsigned short* __restrict__ A, const unsigned short* __restrict__ Bt,
    const float* __restrict__ bias, const float* __restrict__ resid,
    float* __restrict__ C, int M, int N, int K)
{
    constexpr int MI = TM / 32;
    constexpr int NJ = TN / 32;
    constexpr int NLOAD = (TM + TN) / 32;

    __shared__ unsigned short As[TM * 64];
    __shared__ unsigned short Bs[TN * 64];

    const int tid  = threadIdx.x;
    const int wave = tid >> 6;
    const int lane = tid & 63;
    const int m0 = blockIdx.y * TM;
    const int n0 = blockIdx.x * TN;
    const int wm = (wave >> 1) * (TM / 2);
    const int wn = (wave & 1) * (TN / 2);
    const int fr = lane & 15;
    const int kg = lane >> 4;

    int offs[NLOAD];
    unsigned short* lp[NLOAD];
#pragma unroll
    for (int i = 0; i < NLOAD; ++i) {
        const int slot = i * 256 + tid;
        const int row  = slot >> 3;
        const int ch   = slot & 7;
        const int pos  = ch ^ (row & 7);
        if (i < TM / 32) {
            offs[i] = (m0 + row) * K + ch * 8;
            lp[i]   = &As[row * 64 + pos * 8];
        } else {
            const int rb = row - TM;
            offs[i] = (n0 + rb) * K + ch * 8;
            lp[i]   = &Bs[rb * 64 + pos * 8];
        }
    }

    floatx4 acc[MI][NJ] = {};
    bf16x8 pre[NLOAD];

#pragma unroll
    for (int i = 0; i < NLOAD; ++i)
        pre[i] = *(const bf16x8*)((i < TM / 32 ? A : Bt) + offs[i]);
#pragma unroll
    for (int i = 0; i < NLOAD; ++i)
        *(bf16x8*)lp[i] = pre[i];
    __syncthreads();

    for (int kt = 0; kt < K; kt += 64) {
        const bool more = (kt + 64) < K;
        if (more) {
#pragma unroll
            for (int i = 0; i < NLOAD; ++i)
                pre[i] = *(const bf16x8*)((i < TM / 32 ? A : Bt) + offs[i] + kt + 64);
        }

#pragma unroll
        for (int ks = 0; ks < 2; ++ks) {
            const int cq = (ks << 2) | kg;
            bf16x8 af[MI], bfv[NJ];
#pragma unroll
            for (int i = 0; i < MI; ++i) {
                const int row = wm + i * 16 + fr;
                af[i] = *(const bf16x8*)&As[row * 64 + ((cq ^ (row & 7)) << 3)];
            }
#pragma unroll
            for (int j = 0; j < NJ; ++j) {
                const int row = wn + j * 16 + fr;
                bfv[j] = *(const bf16x8*)&Bs[row * 64 + ((cq ^ (row & 7)) << 3)];
            }
#pragma unroll
            for (int i = 0; i < MI; ++i)
#pragma unroll
                for (int j = 0; j < NJ; ++j)
                    acc[i][j] = __builtin_amdgcn_mfma_f32_16x16x32_bf16(
                        af[i], bfv[j], acc[i][j], 0, 0, 0);
        }
        __syncthreads();
        if (more) {
#pragma unroll
            for (int i = 0; i < NLOAD; ++i)
                *(bf16x8*)lp[i] = pre[i];
        }
        __syncthreads();
    }

    const int rq = (lane >> 4) * 4;
    if (MODE == 4) {
        unsigned short* Ct = (unsigned short*)C;
#pragma unroll
        for (int i = 0; i < MI; ++i) {
#pragma unroll
            for (int j = 0; j < NJ; ++j) {
                const int col = n0 + wn + j * 16 + fr;
                const float bv = bias[col];
                const int row0 = m0 + wm + i * 16 + rq;
                ushort4 o;
#pragma unroll
                for (int r = 0; r < 4; ++r)
                    (&o.x)[r] = f2bf(softplus_f(acc[i][j][r] + bv));
                *(ushort4*)&Ct[(size_t)col * M + row0] = o;
            }
        }
    } else {
#pragma unroll
        for (int i = 0; i < MI; ++i) {
#pragma unroll
            for (int j = 0; j < NJ; ++j) {
                const int col = n0 + wn + j * 16 + fr;
                const float bv = bias[col];
#pragma unroll
                for (int r = 0; r < 4; ++r) {
                    const int row = m0 + wm + i * 16 + rq + r;
                    float v = acc[i][j][r] + bv;
                    if (MODE == 1) {
                        v = softplus_f(v);
                    } else if (MODE == 2) {
                        v += resid[(size_t)row * N + col];
                    }
                    C[(size_t)row * N + col] = v;
                }
            }
        }
    }
}

// ---------------------------------------------------------------------------
// Fused depthwise causal conv1d(k=4) + SiLU + x_proj. bf16 x_conv only.
// ---------------------------------------------------------------------------
#define CROWS 4
__global__ __launch_bounds__(256) void conv_xproj(
    const float* __restrict__ xz, const float* __restrict__ conv_w,
    const float* __restrict__ conv_b, const float* __restrict__ W_xp,
    const float* __restrict__ b_xp,
    unsigned short* __restrict__ x_conv_bf, float* __restrict__ BC)
{
    __shared__ float sxc[CROWS][DINNER];   // 32 KB
    __shared__ float red[8][CROWS][32];    // 4 KB

    const int tid = threadIdx.x;
    const int r0 = blockIdx.x * CROWS;
    const int c8 = tid * 8;

    float wt[8][4];
#pragma unroll
    for (int ci = 0; ci < 8; ++ci) {
        float4 w4 = *(const float4*)&conv_w[(c8 + ci) * 4];
        wt[ci][0] = w4.x; wt[ci][1] = w4.y; wt[ci][2] = w4.z; wt[ci][3] = w4.w;
    }
    float cb[8];
    *(float4*)&cb[0] = *(const float4*)&conv_b[c8];
    *(float4*)&cb[4] = *(const float4*)&conv_b[c8 + 4];

#pragma unroll
    for (int rr = 0; rr < CROWS; ++rr) {
        const int row = r0 + rr;
        const int l = row & (L_SEQ - 1);
        float acc[8];
#pragma unroll
        for (int ci = 0; ci < 8; ++ci) acc[ci] = cb[ci];
#pragma unroll
        for (int h = 0; h < 4; ++h) {
            const int lsrc = l - 3 + h;
            if (lsrc >= 0) {
                float4 a = *(const float4*)&xz[(size_t)(row - 3 + h) * (2 * DINNER) + c8];
                float4 b = *(const float4*)&xz[(size_t)(row - 3 + h) * (2 * DINNER) + c8 + 4];
                acc[0] += a.x * wt[0][h]; acc[1] += a.y * wt[1][h];
                acc[2] += a.z * wt[2][h]; acc[3] += a.w * wt[3][h];
                acc[4] += b.x * wt[4][h]; acc[5] += b.y * wt[5][h];
                acc[6] += b.z * wt[6][h]; acc[7] += b.w * wt[7][h];
            }
        }
        float o[8];
        ushort8v ob;
#pragma unroll
        for (int ci = 0; ci < 8; ++ci) {
            o[ci] = silu_f(acc[ci]);
            sxc[rr][c8 + ci] = o[ci];
            ob[ci] = (short)f2bf(o[ci]);
        }
        *(ushort8v*)&x_conv_bf[(size_t)row * DINNER + c8] = ob;
    }
    __syncthreads();

    const int n = tid & 31;
    const int g = tid >> 5;
    float p[CROWS] = {};
    const int k0 = g * 256;
#pragma unroll 4
    for (int k = k0; k < k0 + 256; ++k) {
        const float wv = W_xp[k * 32 + n];
        p[0] += sxc[0][k] * wv;
        p[1] += sxc[1][k] * wv;
        p[2] += sxc[2][k] * wv;
        p[3] += sxc[3][k] * wv;
    }
#pragma unroll
    for (int rr = 0; rr < CROWS; ++rr) red[g][rr][n] = p[rr];
    __syncthreads();
    if (tid < CROWS * 32) {
        const int rr = tid >> 5;
        const int n2 = tid & 31;
        float s = b_xp[n2];
#pragma unroll
        for (int gg = 0; gg < 8; ++gg) s += red[gg][rr][n2];
        BC[(size_t)(r0 + rr) * 32 + n2] = s;
    }
}

// ---------------------------------------------------------------------------
// Chunked two-pass selective scan. bf16 chunk-summary LDS (65.7 KB total)
// -> 2 blocks/CU = 32 waves/CU. launch_bounds(1024,8) pins VGPR<=64.
// ---------------------------------------------------------------------------
__global__ __launch_bounds__(1024, 8) void scan_kernel(
    const unsigned short* __restrict__ deltaT,
    const unsigned short* __restrict__ xc_bf,
    const float* __restrict__ BC, const float* __restrict__ A_log,
    const float* __restrict__ D_skip, const float* __restrict__ xz,
    unsigned short* __restrict__ y_bf)
{
    __shared__ unsigned short sA[DSTATE * SSTR2];   // 32.8 KB
    __shared__ unsigned short sH[DSTATE * SSTR2];   // 32.8 KB

    const int tid = threadIdx.x;
    const int dl  = tid & (DT - 1);
    const int c   = tid >> 4;
    const int b   = blockIdx.x >> 7;
    const int d0  = (blockIdx.x & 127) * DT;
    const int d   = d0 + dl;

    float Al[DSTATE];
#pragma unroll
    for (int s = 0; s < DSTATE; ++s)
        Al[s] = -__expf(A_log[d * DSTATE + s]) * 1.44269504f;
    const float Dsk = D_skip[d];

    const int l0 = c * CS;
    const int row0 = b * L_SEQ + l0;

    const unsigned short* dpt = deltaT + (size_t)d * (B_SZ * L_SEQ) + row0;
    bf16x8 dv0 = *(const bf16x8*)dpt;
    bf16x8 dv1 = *(const bf16x8*)(dpt + 8);
    float dts[CS];
    float dsum = 0.f;
#pragma unroll
    for (int k = 0; k < 8; ++k) {
        dts[k]     = bf2f((unsigned short)dv0[k]);
        dts[8 + k] = bf2f((unsigned short)dv1[k]);
    }
#pragma unroll
    for (int k = 0; k < CS; ++k) dsum += dts[k];

    float h[DSTATE];
#pragma unroll
    for (int s = 0; s < DSTATE; ++s) h[s] = 0.f;

    const unsigned short* xcp = xc_bf + (size_t)row0 * DINNER + d;
    const float* bcp = BC + (size_t)row0 * 32;

    // ---- pass 1: chunk summaries from h=0 ----
#pragma unroll 4
    for (int j = 0; j < CS; ++j) {
        const float dt = dts[j];
        const float xc = bf2f(xcp[j * DINNER]);
        float Bv[DSTATE];
        *(float4*)&Bv[0]  = *(const float4*)(bcp + j * 32 + 0);
        *(float4*)&Bv[4]  = *(const float4*)(bcp + j * 32 + 4);
        *(float4*)&Bv[8]  = *(const float4*)(bcp + j * 32 + 8);
        *(float4*)&Bv[12] = *(const float4*)(bcp + j * 32 + 12);
        const float dlx = dt * xc;
#pragma unroll
        for (int s = 0; s < DSTATE; ++s) {
            const float e = nexp2(dt * Al[s]);
            h[s] = e * h[s] + dlx * Bv[s];
        }
    }
#pragma unroll
    for (int s = 0; s < DSTATE; ++s) {
        sH[s * SSTR2 + c * DT + dl] = f2bf(h[s]);
        sA[s * SSTR2 + c * DT + dl] = f2bf(nexp2(Al[s] * dsum));
    }
    __syncthreads();

    // ---- combine: sequential over chunks, parallel over (s, dl) ----
    if (tid < DSTATE * DT) {
        const int dl2 = tid & (DT - 1);
        const int s2  = tid >> 4;
        float hh = 0.f;
#pragma unroll
        for (int c2 = 0; c2 < CCH; ++c2) {
            const int idx = s2 * SSTR2 + c2 * DT + dl2;
            const float a  = bf2f(sA[idx]);
            const float he = bf2f(sH[idx]);
            sH[idx] = f2bf(hh);
            hh = a * hh + he;
        }
    }
    __syncthreads();

#pragma unroll
    for (int s = 0; s < DSTATE; ++s) h[s] = bf2f(sH[s * SSTR2 + c * DT + dl]);

    // ---- pass 2: rescan with true h0, fuse D_skip + silu(z) gate ----
    const float* zp = xz + (size_t)row0 * (2 * DINNER) + DINNER + d;
    unsigned short* yp = y_bf + (size_t)row0 * DINNER + d;
#pragma unroll 4
    for (int j = 0; j < CS; ++j) {
        const float dt = dts[j];
        const float xc = bf2f(xcp[j * DINNER]);
        const float z  = zp[j * (2 * DINNER)];
        float Bv[DSTATE], Cv[DSTATE];
        *(float4*)&Bv[0]  = *(const float4*)(bcp + j * 32 + 0);
        *(float4*)&Bv[4]  = *(const float4*)(bcp + j * 32 + 4);
        *(float4*)&Bv[8]  = *(const float4*)(bcp + j * 32 + 8);
        *(float4*)&Bv[12] = *(const float4*)(bcp + j * 32 + 12);
        *(float4*)&Cv[0]  = *(const float4*)(bcp + j * 32 + 16);
        *(float4*)&Cv[4]  = *(const float4*)(bcp + j * 32 + 20);
        *(float4*)&Cv[8]  = *(const float4*)(bcp + j * 32 + 24);
        *(float4*)&Cv[12] = *(const float4*)(bcp + j * 32 + 28);
        const float dlx = dt * xc;
        float y = Dsk * xc;
#pragma unroll
        for (int s = 0; s < DSTATE; ++s) {
            const float e = nexp2(dt * Al[s]);
            h[s] = e * h[s] + dlx * Bv[s];
            y += h[s] * Cv[s];
        }
        yp[j * DINNER] = f2bf(y * silu_f(z));
    }
}

// ---------------------------------------------------------------------------
// Row LayerNorm: unbiased variance (N-1), eps added to std.
// ---------------------------------------------------------------------------
__global__ __launch_bounds__(256) void layernorm_kernel(
    const float* __restrict__ t, const float* __restrict__ alpha,
    const float* __restrict__ beta, float* __restrict__ out)
{
    __shared__ float sred[4];
    __shared__ float sred2[4];
    const int row = blockIdx.x;
    const int tid = threadIdx.x;
    const float* r = t + (size_t)row * DMODEL;

    float4 v = *(const float4*)&r[tid * 4];
    float lsum = v.x + v.y + v.z + v.w;
#pragma unroll
    for (int m = 1; m < 64; m <<= 1) lsum += __shfl_xor(lsum, m);
    if ((tid & 63) == 0) sred[tid >> 6] = lsum;
    __syncthreads();
    const float mean = (sred[0] + sred[1] + sred[2] + sred[3]) * (1.f / DMODEL);

    const float dx = v.x - mean, dy = v.y - mean, dz = v.z - mean, dw = v.w - mean;
    float ls2 = dx * dx + dy * dy + dz * dz + dw * dw;
#pragma unroll
    for (int m = 1; m < 64; m <<= 1) ls2 += __shfl_xor(ls2, m);
    if ((tid & 63) == 0) sred2[tid >> 6] = ls2;
    __syncthreads();
    const float var = (sred2[0] + sred2[1] + sred2[2] + sred2[3]) * (1.f / (DMODEL - 1));
    const float inv = 1.f / (sqrtf(var) + EPSV);

    float4 a4 = *(const float4*)&alpha[tid * 4];
    float4 b4 = *(const float4*)&beta[tid * 4];
    float4 o;
    o.x = a4.x * dx * inv + b4.x;
    o.y = a4.y * dy * inv + b4.y;
    o.z = a4.z * dz * inv + b4.z;
    o.w = a4.w * dw * inv + b4.w;
    *(float4*)&out[(size_t)row * DMODEL + tid * 4] = o;
}

// ---------------------------------------------------------------------------
extern "C" void kernel_launch(void* const* d_in, const int* in_sizes, int n_in,
                              void* d_out, int out_size, void* d_ws, size_t ws_size,
                              hipStream_t stream)
{
    const float* x      = (const float*)d_in[0];
    const float* W_in   = (const float*)d_in[1];
    const float* b_in   = (const float*)d_in[2];
    const float* conv_w = (const float*)d_in[3];
    const float* conv_b = (const float*)d_in[4];
    const float* W_xp   = (const float*)d_in[5];
    const float* b_xp   = (const float*)d_in[6];
    const float* W_dt   = (const float*)d_in[7];
    const float* b_dt   = (const float*)d_in[8];
    const float* A_log  = (const float*)d_in[9];
    const float* D_skip = (const float*)d_in[10];
    const float* W_out  = (const float*)d_in[11];
    const float* b_out  = (const float*)d_in[12];
    const float* alpha  = (const float*)d_in[13];
    const float* beta   = (const float*)d_in[14];
    float* out = (float*)d_out;

    const size_t M = (size_t)B_SZ * L_SEQ;  // 2048 rows
    char* ws = (char*)d_ws;
    float* xz      = (float*)(ws + 0);                  // 32 MB (reused as tpre)
    unsigned short* deltaT = (unsigned short*)(ws + (48u << 20));  // 8 MB, [D][B*L]
    float* BC      = (float*)(ws + (64u << 20));        // 0.5 MB
    unsigned short* x_bf       = (unsigned short*)(ws + (64u << 20) + (512u << 10)); // 4 MB
    unsigned short* W_in_t     = (unsigned short*)(ws + (69u << 20));  // 8 MB
    unsigned short* W_dt_t     = (unsigned short*)(ws + (77u << 20));  // 8 MB
    unsigned short* W_out_t    = (unsigned short*)(ws + (85u << 20));  // 4 MB
    unsigned short* x_conv_bf  = (unsigned short*)(ws + (89u << 20));  // 8 MB
    unsigned short* ygate_bf   = (unsigned short*)(ws + (77u << 20));  // reuse W_dt_t
    float* tpre = xz;

    const dim3 blk(256);

    // 0. fused prep: weight transposes + x cast
    prep_kernel<<<dim3(12288), blk, 0, stream>>>(
        x, x_bf, W_in, W_in_t, W_dt, W_dt_t, W_out, W_out_t);

    // 1. xz = x @ W_in + b_in  (2048 x 4096 x 1024), 128x128, 512 blocks
    gemm_bf16<128, 128, 0, 2><<<dim3(4096 / 128, 2048 / 128), blk, 0, stream>>>(
        x_bf, W_in_t, b_in, nullptr, xz, 2048, 4096, 1024);

    // 2+3. conv + SiLU + x_proj (fused)
    conv_xproj<<<dim3((unsigned)(M / CROWS)), blk, 0, stream>>>(
        xz, conv_w, conv_b, W_xp, b_xp, x_conv_bf, BC);

    // 4. deltaT = softplus(x_conv @ W_dt + b_dt)^T -> bf16 [D][B*L],
    //    128x64 tiles -> 512 blocks = 2/CU
    gemm_bf16<128, 64, 4, 3><<<dim3(2048 / 64, 2048 / 128), blk, 0, stream>>>(
        x_conv_bf, W_dt_t, b_dt, nullptr, (float*)deltaT, 2048, 2048, 2048);

    // 5. chunked two-pass selective scan + D_skip + z-gate -> bf16
    scan_kernel<<<dim3(B_SZ * (DINNER / DT)), dim3(1024), 0, stream>>>(
        deltaT, x_conv_bf, BC, A_log, D_skip, xz, ygate_bf);

    // 6. tpre = ygate @ W_out + b_out + x  (2048 x 1024 x 2048), 512 blocks
    gemm_bf16<64, 64, 2, 3><<<dim3(1024 / 64, 2048 / 64), blk, 0, stream>>>(
        ygate_bf, W_out_t, b_out, x, tpre, 2048, 1024, 2048);

    // 7. LayerNorm
    layernorm_kernel<<<dim3((unsigned)M), blk, 0, stream>>>(tpre, alpha, beta, out);
}

// Round 11
// 261.959 us; speedup vs baseline: 1.3923x; 1.3923x over previous
//
#include <hip/hip_runtime.h>
#include <math.h>

#define B_SZ    2
#define L_SEQ   1024
#define DMODEL  1024
#define DINNER  2048
#define DSTATE  16
#define EPSV    1e-6f

// scan decomposition: 16 channels/block, 64 chunks of 16 steps, 1024 thr/block
#define CCH 64
#define CS  (L_SEQ / CCH)      // 16
#define DT  16
#define SSTR2 (CCH * DT + 2)   // +2 ushort pad (1 dword) to stagger s-groups

typedef short  bf16x8  __attribute__((ext_vector_type(8)));
typedef float  floatx4 __attribute__((ext_vector_type(4)));
typedef unsigned short ushort8v __attribute__((ext_vector_type(8)));

extern "C" __device__ float __ocml_native_exp2_f32(float);
extern "C" __device__ float __ocml_native_log2_f32(float);

__device__ __forceinline__ float nexp2(float x) { return __ocml_native_exp2_f32(x); }

__device__ __forceinline__ float softplus_f(float v) {
    if (v > 20.f) return v;
    return 0.69314718f * __ocml_native_log2_f32(1.f + nexp2(v * 1.44269504f));
}
__device__ __forceinline__ float silu_f(float z) {
    return z / (1.f + nexp2(z * -1.44269504f));
}

__device__ __forceinline__ unsigned short f2bf(float f) {
    unsigned int u = __float_as_uint(f);
    unsigned int r = (u + 0x7FFFu + ((u >> 16) & 1u)) >> 16;
    return (unsigned short)r;
}
__device__ __forceinline__ float bf2f(unsigned short u) {
    return __uint_as_float(((unsigned int)u) << 16);
}

// ---------------------------------------------------------------------------
// Fused prep: 3 weight transposes (+cast) and the x cast, one launch.
// ---------------------------------------------------------------------------
__global__ __launch_bounds__(256) void prep_kernel(
    const float* __restrict__ x, unsigned short* __restrict__ x_bf,
    const float* __restrict__ W_in, unsigned short* __restrict__ W_in_t,
    const float* __restrict__ W_dt, unsigned short* __restrict__ W_dt_t,
    const float* __restrict__ W_out, unsigned short* __restrict__ W_out_t)
{
    const int bid = blockIdx.x;
    if (bid >= 10240) {
        const int i = (bid - 10240) * 256 + threadIdx.x;
        float4 v = ((const float4*)x)[i];
        ushort4 o = { f2bf(v.x), f2bf(v.y), f2bf(v.z), f2bf(v.w) };
        ((ushort4*)x_bf)[i] = o;
        return;
    }
    __shared__ float tile[32][33];
    const float* W; unsigned short* Wt; int K, N, t;
    if (bid < 4096)      { W = W_in;  Wt = W_in_t;  K = 1024; N = 4096; t = bid; }
    else if (bid < 8192) { W = W_dt;  Wt = W_dt_t;  K = 2048; N = 2048; t = bid - 4096; }
    else                 { W = W_out; Wt = W_out_t; K = 2048; N = 1024; t = bid - 8192; }
    const int nx = N >> 5;
    const int n0 = (t % nx) * 32;
    const int k0 = (t / nx) * 32;
    const int c = threadIdx.x & 31;
    const int r = threadIdx.x >> 5;
#pragma unroll
    for (int i = 0; i < 4; ++i)
        tile[r + 8 * i][c] = W[(size_t)(k0 + r + 8 * i) * N + n0 + c];
    __syncthreads();
#pragma unroll
    for (int i = 0; i < 4; ++i)
        Wt[(size_t)(n0 + r + 8 * i) * K + k0 + c] = f2bf(tile[c][r + 8 * i]);
}

// ---------------------------------------------------------------------------
// bf16 MFMA GEMM — register-prefetch, single-buffered LDS, BK=64.
// 2x2 waves, wave tile (TM/2)x(TN/2). XOR-swizzled, vmcnt drains post-compute.
// MODE 0: +bias; 1: softplus(+bias); 2: +bias + resid;
// 4: softplus(+bias) -> bf16 TRANSPOSED output Ct[col][row]
// ---------------------------------------------------------------------------
template <int TM, int TN, int MODE, int MINW>
__global__ __launch_bounds__(256, MINW) void gemm_bf16(
    const unsigned short* __restrict__ A, const unsigned short* __restrict__ Bt,
    const float* __restrict__ bias, const float* __restrict__ resid,
    float* __restrict__ C, int M, int N, int K)
{
    constexpr int MI = TM / 32;
    constexpr int NJ = TN / 32;
    constexpr int NLOAD = (TM + TN) / 32;

    __shared__ unsigned short As[TM * 64];
    __shared__ unsigned short Bs[TN * 64];

    const int tid  = threadIdx.x;
    const int wave = tid >> 6;
    const int lane = tid & 63;
    const int m0 = blockIdx.y * TM;
    const int n0 = blockIdx.x * TN;
    const int wm = (wave >> 1) * (TM / 2);
    const int wn = (wave & 1) * (TN / 2);
    const int fr = lane & 15;
    const int kg = lane >> 4;

    int offs[NLOAD];
    unsigned short* lp[NLOAD];
#pragma unroll
    for (int i = 0; i < NLOAD; ++i) {
        const int slot = i * 256 + tid;
        const int row  = slot >> 3;
        const int ch   = slot & 7;
        const int pos  = ch ^ (row & 7);
        if (i < TM / 32) {
            offs[i] = (m0 + row) * K + ch * 8;
            lp[i]   = &As[row * 64 + pos * 8];
        } else {
            const int rb = row - TM;
            offs[i] = (n0 + rb) * K + ch * 8;
            lp[i]   = &Bs[rb * 64 + pos * 8];
        }
    }

    floatx4 acc[MI][NJ] = {};
    bf16x8 pre[NLOAD];

#pragma unroll
    for (int i = 0; i < NLOAD; ++i)
        pre[i] = *(const bf16x8*)((i < TM / 32 ? A : Bt) + offs[i]);
#pragma unroll
    for (int i = 0; i < NLOAD; ++i)
        *(bf16x8*)lp[i] = pre[i];
    __syncthreads();

    for (int kt = 0; kt < K; kt += 64) {
        const bool more = (kt + 64) < K;
        if (more) {
#pragma unroll
            for (int i = 0; i < NLOAD; ++i)
                pre[i] = *(const bf16x8*)((i < TM / 32 ? A : Bt) + offs[i] + kt + 64);
        }

#pragma unroll
        for (int ks = 0; ks < 2; ++ks) {
            const int cq = (ks << 2) | kg;
            bf16x8 af[MI], bfv[NJ];
#pragma unroll
            for (int i = 0; i < MI; ++i) {
                const int row = wm + i * 16 + fr;
                af[i] = *(const bf16x8*)&As[row * 64 + ((cq ^ (row & 7)) << 3)];
            }
#pragma unroll
            for (int j = 0; j < NJ; ++j) {
                const int row = wn + j * 16 + fr;
                bfv[j] = *(const bf16x8*)&Bs[row * 64 + ((cq ^ (row & 7)) << 3)];
            }
#pragma unroll
            for (int i = 0; i < MI; ++i)
#pragma unroll
                for (int j = 0; j < NJ; ++j)
                    acc[i][j] = __builtin_amdgcn_mfma_f32_16x16x32_bf16(
                        af[i], bfv[j], acc[i][j], 0, 0, 0);
        }
        __syncthreads();
        if (more) {
#pragma unroll
            for (int i = 0; i < NLOAD; ++i)
                *(bf16x8*)lp[i] = pre[i];
        }
        __syncthreads();
    }

    const int rq = (lane >> 4) * 4;
    if (MODE == 4) {
        unsigned short* Ct = (unsigned short*)C;
#pragma unroll
        for (int i = 0; i < MI; ++i) {
#pragma unroll
            for (int j = 0; j < NJ; ++j) {
                const int col = n0 + wn + j * 16 + fr;
                const float bv = bias[col];
                const int row0 = m0 + wm + i * 16 + rq;
                ushort4 o;
#pragma unroll
                for (int r = 0; r < 4; ++r)
                    (&o.x)[r] = f2bf(softplus_f(acc[i][j][r] + bv));
                *(ushort4*)&Ct[(size_t)col * M + row0] = o;
            }
        }
    } else {
#pragma unroll
        for (int i = 0; i < MI; ++i) {
#pragma unroll
            for (int j = 0; j < NJ; ++j) {
                const int col = n0 + wn + j * 16 + fr;
                const float bv = bias[col];
#pragma unroll
                for (int r = 0; r < 4; ++r) {
                    const int row = m0 + wm + i * 16 + rq + r;
                    float v = acc[i][j][r] + bv;
                    if (MODE == 1) {
                        v = softplus_f(v);
                    } else if (MODE == 2) {
                        v += resid[(size_t)row * N + col];
                    }
                    C[(size_t)row * N + col] = v;
                }
            }
        }
    }
}

// ---------------------------------------------------------------------------
// Fused depthwise causal conv1d(k=4) + SiLU + x_proj. bf16 x_conv only.
// ---------------------------------------------------------------------------
#define CROWS 4
__global__ __launch_bounds__(256) void conv_xproj(
    const float* __restrict__ xz, const float* __restrict__ conv_w,
    const float* __restrict__ conv_b, const float* __restrict__ W_xp,
    const float* __restrict__ b_xp,
    unsigned short* __restrict__ x_conv_bf, float* __restrict__ BC)
{
    __shared__ float sxc[CROWS][DINNER];   // 32 KB
    __shared__ float red[8][CROWS][32];    // 4 KB

    const int tid = threadIdx.x;
    const int r0 = blockIdx.x * CROWS;
    const int c8 = tid * 8;

    float wt[8][4];
#pragma unroll
    for (int ci = 0; ci < 8; ++ci) {
        float4 w4 = *(const float4*)&conv_w[(c8 + ci) * 4];
        wt[ci][0] = w4.x; wt[ci][1] = w4.y; wt[ci][2] = w4.z; wt[ci][3] = w4.w;
    }
    float cb[8];
    *(float4*)&cb[0] = *(const float4*)&conv_b[c8];
    *(float4*)&cb[4] = *(const float4*)&conv_b[c8 + 4];

#pragma unroll
    for (int rr = 0; rr < CROWS; ++rr) {
        const int row = r0 + rr;
        const int l = row & (L_SEQ - 1);
        float acc[8];
#pragma unroll
        for (int ci = 0; ci < 8; ++ci) acc[ci] = cb[ci];
#pragma unroll
        for (int h = 0; h < 4; ++h) {
            const int lsrc = l - 3 + h;
            if (lsrc >= 0) {
                float4 a = *(const float4*)&xz[(size_t)(row - 3 + h) * (2 * DINNER) + c8];
                float4 b = *(const float4*)&xz[(size_t)(row - 3 + h) * (2 * DINNER) + c8 + 4];
                acc[0] += a.x * wt[0][h]; acc[1] += a.y * wt[1][h];
                acc[2] += a.z * wt[2][h]; acc[3] += a.w * wt[3][h];
                acc[4] += b.x * wt[4][h]; acc[5] += b.y * wt[5][h];
                acc[6] += b.z * wt[6][h]; acc[7] += b.w * wt[7][h];
            }
        }
        float o[8];
        ushort8v ob;
#pragma unroll
        for (int ci = 0; ci < 8; ++ci) {
            o[ci] = silu_f(acc[ci]);
            sxc[rr][c8 + ci] = o[ci];
            ob[ci] = (short)f2bf(o[ci]);
        }
        *(ushort8v*)&x_conv_bf[(size_t)row * DINNER + c8] = ob;
    }
    __syncthreads();

    const int n = tid & 31;
    const int g = tid >> 5;
    float p[CROWS] = {};
    const int k0 = g * 256;
#pragma unroll 4
    for (int k = k0; k < k0 + 256; ++k) {
        const float wv = W_xp[k * 32 + n];
        p[0] += sxc[0][k] * wv;
        p[1] += sxc[1][k] * wv;
        p[2] += sxc[2][k] * wv;
        p[3] += sxc[3][k] * wv;
    }
#pragma unroll
    for (int rr = 0; rr < CROWS; ++rr) red[g][rr][n] = p[rr];
    __syncthreads();
    if (tid < CROWS * 32) {
        const int rr = tid >> 5;
        const int n2 = tid & 31;
        float s = b_xp[n2];
#pragma unroll
        for (int gg = 0; gg < 8; ++gg) s += red[gg][rr][n2];
        BC[(size_t)(r0 + rr) * 32 + n2] = s;
    }
}

// ---------------------------------------------------------------------------
// Chunked two-pass selective scan. bf16 chunk-summary LDS (65.7 KB total).
// launch_bounds(1024, 4): VGPR cap 128 -> NO spill (round-10 lesson: the
// (1024,8) cap of 64... allocator gave 32 and spilled 81 MB to scratch).
// If compiler lands <=64 VGPR, HW gives 2 blocks/CU; else 1 (round-8 parity).
// ---------------------------------------------------------------------------
__global__ __launch_bounds__(1024, 4) void scan_kernel(
    const unsigned short* __restrict__ deltaT,
    const unsigned short* __restrict__ xc_bf,
    const float* __restrict__ BC, const float* __restrict__ A_log,
    const float* __restrict__ D_skip, const float* __restrict__ xz,
    unsigned short* __restrict__ y_bf)
{
    __shared__ unsigned short sA[DSTATE * SSTR2];   // 32.8 KB
    __shared__ unsigned short sH[DSTATE * SSTR2];   // 32.8 KB

    const int tid = threadIdx.x;
    const int dl  = tid & (DT - 1);
    const int c   = tid >> 4;
    const int b   = blockIdx.x >> 7;
    const int d0  = (blockIdx.x & 127) * DT;
    const int d   = d0 + dl;

    float Al[DSTATE];
#pragma unroll
    for (int s = 0; s < DSTATE; ++s)
        Al[s] = -__expf(A_log[d * DSTATE + s]) * 1.44269504f;
    const float Dsk = D_skip[d];

    const int l0 = c * CS;
    const int row0 = b * L_SEQ + l0;

    const unsigned short* dpt = deltaT + (size_t)d * (B_SZ * L_SEQ) + row0;
    bf16x8 dv0 = *(const bf16x8*)dpt;
    bf16x8 dv1 = *(const bf16x8*)(dpt + 8);
    float dts[CS];
    float dsum = 0.f;
#pragma unroll
    for (int k = 0; k < 8; ++k) {
        dts[k]     = bf2f((unsigned short)dv0[k]);
        dts[8 + k] = bf2f((unsigned short)dv1[k]);
    }
#pragma unroll
    for (int k = 0; k < CS; ++k) dsum += dts[k];

    float h[DSTATE];
#pragma unroll
    for (int s = 0; s < DSTATE; ++s) h[s] = 0.f;

    const unsigned short* xcp = xc_bf + (size_t)row0 * DINNER + d;
    const float* bcp = BC + (size_t)row0 * 32;

    // ---- pass 1: chunk summaries from h=0 ----
#pragma unroll 4
    for (int j = 0; j < CS; ++j) {
        const float dt = dts[j];
        const float xc = bf2f(xcp[j * DINNER]);
        float Bv[DSTATE];
        *(float4*)&Bv[0]  = *(const float4*)(bcp + j * 32 + 0);
        *(float4*)&Bv[4]  = *(const float4*)(bcp + j * 32 + 4);
        *(float4*)&Bv[8]  = *(const float4*)(bcp + j * 32 + 8);
        *(float4*)&Bv[12] = *(const float4*)(bcp + j * 32 + 12);
        const float dlx = dt * xc;
#pragma unroll
        for (int s = 0; s < DSTATE; ++s) {
            const float e = nexp2(dt * Al[s]);
            h[s] = e * h[s] + dlx * Bv[s];
        }
    }
#pragma unroll
    for (int s = 0; s < DSTATE; ++s) {
        sH[s * SSTR2 + c * DT + dl] = f2bf(h[s]);
        sA[s * SSTR2 + c * DT + dl] = f2bf(nexp2(Al[s] * dsum));
    }
    __syncthreads();

    // ---- combine: sequential over chunks, parallel over (s, dl) ----
    if (tid < DSTATE * DT) {
        const int dl2 = tid & (DT - 1);
        const int s2  = tid >> 4;
        float hh = 0.f;
#pragma unroll
        for (int c2 = 0; c2 < CCH; ++c2) {
            const int idx = s2 * SSTR2 + c2 * DT + dl2;
            const float a  = bf2f(sA[idx]);
            const float he = bf2f(sH[idx]);
            sH[idx] = f2bf(hh);
            hh = a * hh + he;
        }
    }
    __syncthreads();

#pragma unroll
    for (int s = 0; s < DSTATE; ++s) h[s] = bf2f(sH[s * SSTR2 + c * DT + dl]);

    // ---- pass 2: rescan with true h0, fuse D_skip + silu(z) gate ----
    const float* zp = xz + (size_t)row0 * (2 * DINNER) + DINNER + d;
    unsigned short* yp = y_bf + (size_t)row0 * DINNER + d;
#pragma unroll 4
    for (int j = 0; j < CS; ++j) {
        const float dt = dts[j];
        const float xc = bf2f(xcp[j * DINNER]);
        const float z  = zp[j * (2 * DINNER)];
        float Bv[DSTATE], Cv[DSTATE];
        *(float4*)&Bv[0]  = *(const float4*)(bcp + j * 32 + 0);
        *(float4*)&Bv[4]  = *(const float4*)(bcp + j * 32 + 4);
        *(float4*)&Bv[8]  = *(const float4*)(bcp + j * 32 + 8);
        *(float4*)&Bv[12] = *(const float4*)(bcp + j * 32 + 12);
        *(float4*)&Cv[0]  = *(const float4*)(bcp + j * 32 + 16);
        *(float4*)&Cv[4]  = *(const float4*)(bcp + j * 32 + 20);
        *(float4*)&Cv[8]  = *(const float4*)(bcp + j * 32 + 24);
        *(float4*)&Cv[12] = *(const float4*)(bcp + j * 32 + 28);
        const float dlx = dt * xc;
        float y = Dsk * xc;
#pragma unroll
        for (int s = 0; s < DSTATE; ++s) {
            const float e = nexp2(dt * Al[s]);
            h[s] = e * h[s] + dlx * Bv[s];
            y += h[s] * Cv[s];
        }
        yp[j * DINNER] = f2bf(y * silu_f(z));
    }
}

// ---------------------------------------------------------------------------
// Row LayerNorm: unbiased variance (N-1), eps added to std.
// ---------------------------------------------------------------------------
__global__ __launch_bounds__(256) void layernorm_kernel(
    const float* __restrict__ t, const float* __restrict__ alpha,
    const float* __restrict__ beta, float* __restrict__ out)
{
    __shared__ float sred[4];
    __shared__ float sred2[4];
    const int row = blockIdx.x;
    const int tid = threadIdx.x;
    const float* r = t + (size_t)row * DMODEL;

    float4 v = *(const float4*)&r[tid * 4];
    float lsum = v.x + v.y + v.z + v.w;
#pragma unroll
    for (int m = 1; m < 64; m <<= 1) lsum += __shfl_xor(lsum, m);
    if ((tid & 63) == 0) sred[tid >> 6] = lsum;
    __syncthreads();
    const float mean = (sred[0] + sred[1] + sred[2] + sred[3]) * (1.f / DMODEL);

    const float dx = v.x - mean, dy = v.y - mean, dz = v.z - mean, dw = v.w - mean;
    float ls2 = dx * dx + dy * dy + dz * dz + dw * dw;
#pragma unroll
    for (int m = 1; m < 64; m <<= 1) ls2 += __shfl_xor(ls2, m);
    if ((tid & 63) == 0) sred2[tid >> 6] = ls2;
    __syncthreads();
    const float var = (sred2[0] + sred2[1] + sred2[2] + sred2[3]) * (1.f / (DMODEL - 1));
    const float inv = 1.f / (sqrtf(var) + EPSV);

    float4 a4 = *(const float4*)&alpha[tid * 4];
    float4 b4 = *(const float4*)&beta[tid * 4];
    float4 o;
    o.x = a4.x * dx * inv + b4.x;
    o.y = a4.y * dy * inv + b4.y;
    o.z = a4.z * dz * inv + b4.z;
    o.w = a4.w * dw * inv + b4.w;
    *(float4*)&out[(size_t)row * DMODEL + tid * 4] = o;
}

// ---------------------------------------------------------------------------
extern "C" void kernel_launch(void* const* d_in, const int* in_sizes, int n_in,
                              void* d_out, int out_size, void* d_ws, size_t ws_size,
                              hipStream_t stream)
{
    const float* x      = (const float*)d_in[0];
    const float* W_in   = (const float*)d_in[1];
    const float* b_in   = (const float*)d_in[2];
    const float* conv_w = (const float*)d_in[3];
    const float* conv_b = (const float*)d_in[4];
    const float* W_xp   = (const float*)d_in[5];
    const float* b_xp   = (const float*)d_in[6];
    const float* W_dt   = (const float*)d_in[7];
    const float* b_dt   = (const float*)d_in[8];
    const float* A_log  = (const float*)d_in[9];
    const float* D_skip = (const float*)d_in[10];
    const float* W_out  = (const float*)d_in[11];
    const float* b_out  = (const float*)d_in[12];
    const float* alpha  = (const float*)d_in[13];
    const float* beta   = (const float*)d_in[14];
    float* out = (float*)d_out;

    const size_t M = (size_t)B_SZ * L_SEQ;  // 2048 rows
    char* ws = (char*)d_ws;
    float* xz      = (float*)(ws + 0);                  // 32 MB (reused as tpre)
    unsigned short* deltaT = (unsigned short*)(ws + (48u << 20));  // 8 MB, [D][B*L]
    float* BC      = (float*)(ws + (64u << 20));        // 0.5 MB
    unsigned short* x_bf       = (unsigned short*)(ws + (64u << 20) + (512u << 10)); // 4 MB
    unsigned short* W_in_t     = (unsigned short*)(ws + (69u << 20));  // 8 MB
    unsigned short* W_dt_t     = (unsigned short*)(ws + (77u << 20));  // 8 MB
    unsigned short* W_out_t    = (unsigned short*)(ws + (85u << 20));  // 4 MB
    unsigned short* x_conv_bf  = (unsigned short*)(ws + (89u << 20));  // 8 MB
    unsigned short* ygate_bf   = (unsigned short*)(ws + (77u << 20));  // reuse W_dt_t
    float* tpre = xz;

    const dim3 blk(256);

    // 0. fused prep: weight transposes + x cast
    prep_kernel<<<dim3(12288), blk, 0, stream>>>(
        x, x_bf, W_in, W_in_t, W_dt, W_dt_t, W_out, W_out_t);

    // 1. xz = x @ W_in + b_in  (2048 x 4096 x 1024), 128x128, 512 blocks
    gemm_bf16<128, 128, 0, 2><<<dim3(4096 / 128, 2048 / 128), blk, 0, stream>>>(
        x_bf, W_in_t, b_in, nullptr, xz, 2048, 4096, 1024);

    // 2+3. conv + SiLU + x_proj (fused)
    conv_xproj<<<dim3((unsigned)(M / CROWS)), blk, 0, stream>>>(
        xz, conv_w, conv_b, W_xp, b_xp, x_conv_bf, BC);

    // 4. deltaT = softplus(x_conv @ W_dt + b_dt)^T -> bf16 [D][B*L],
    //    128x64 tiles -> 512 blocks = 2/CU
    gemm_bf16<128, 64, 4, 3><<<dim3(2048 / 64, 2048 / 128), blk, 0, stream>>>(
        x_conv_bf, W_dt_t, b_dt, nullptr, (float*)deltaT, 2048, 2048, 2048);

    // 5. chunked two-pass selective scan + D_skip + z-gate -> bf16
    scan_kernel<<<dim3(B_SZ * (DINNER / DT)), dim3(1024), 0, stream>>>(
        deltaT, x_conv_bf, BC, A_log, D_skip, xz, ygate_bf);

    // 6. tpre = ygate @ W_out + b_out + x  (2048 x 1024 x 2048), 512 blocks
    gemm_bf16<64, 64, 2, 3><<<dim3(1024 / 64, 2048 / 64), blk, 0, stream>>>(
        ygate_bf, W_out_t, b_out, x, tpre, 2048, 1024, 2048);

    // 7. LayerNorm
    layernorm_kernel<<<dim3((unsigned)M), blk, 0, stream>>>(tpre, alpha, beta, out);
}